// Round 9
// baseline (7108.602 us; speedup 1.0000x reference)
//
#include <hip/hip_runtime.h>

// ---------------- problem constants ----------------
#define S_LEN 512
#define NWG   64
#define COLS  48
#define OUT_ALLH (512*64*512)
#define OUT_SH   (OUT_ALLH)
#define OUT_SC   (OUT_ALLH + 64*512)

// ---------------- ws layout (bytes) ----------------
#define O_WT    0ull
#define SZ_WT   (3072ull*1024*2)             // bf16 [3072][1024] (row n = q*512+col)
#define O_BIAS  (O_WT + SZ_WT)
#define SZ_BIAS (3072ull*4)
#define O_HBF   (O_BIAS + SZ_BIAS)           // u16 [g][buf][wg][32][8]: g*32768 + buf*16384 + wg*256 + r*8 + c
#define SZ_HBF  (2ull*2*64*32*8*2)           // 131072
#define O_FLAG  (O_HBF + SZ_HBF)             // int flagA[64]; flagB[64]
#define SZ_FLAG (512ull)
#define O_P     (O_FLAG + SZ_FLAG)           // f32 [g][wg][64]: g*4096 + wg*64 + gi*32 + r
#define SZ_P    (2ull*64*64*4)               // 32768
#define O_XBF   (O_P + SZ_P)
#define SZ_XBF  (512ull*64*512*2)
#define WS_FULL (O_XBF + SZ_XBF)

// ---------------- LDS layout (bytes) ----------------
#define L_WLDS  0                  // 98304
#define L_PLDS  98304              // 64*68*4 = 17408
#define L_GATES 115712             // 2 * 32*53*4 = 13568
#define L_PART  129280             // 64*4*2*4 = 2048
#define L_CST   131328             // 2*32*9*4 = 2304
#define L_BLDS  133632             // 192
#define L_SLEN  133824             // 256
#define SMEM_TOTAL 134080

typedef short bf16x8 __attribute__((ext_vector_type(8)));
typedef float f32x4  __attribute__((ext_vector_type(4)));

__device__ __forceinline__ unsigned short f2bf(float f) {
  unsigned u = __float_as_uint(f);
  u += 0x7fffu + ((u >> 16) & 1u);
  return (unsigned short)(u >> 16);
}

#define ATOM_LD(p)    __hip_atomic_load((p), __ATOMIC_RELAXED, __HIP_MEMORY_SCOPE_AGENT)
#define ATOM_ST(p, v) __hip_atomic_store((p), (v), __ATOMIC_RELAXED, __HIP_MEMORY_SCOPE_AGENT)

struct PrepArgs {
  const float* W[6]; const float* bia[6];
  const float* h0;
  unsigned short* WT; float* bias_all; unsigned short* Hbf;
  int* flag;
};

__global__ void prep_kernel(PrepArgs a) {
  const int n = blockIdx.x, tid = threadIdx.x;
  if (n < 3072) {
    const int q = n >> 9, col = n & 511;
    const float* Wq = a.W[q];
    for (int k = tid; k < 1024; k += 256)
      a.WT[(size_t)n*1024 + k] = f2bf(Wq[k*512 + col]);
    if (tid == 0) a.bias_all[n] = a.bia[q][col];
  } else if (n < 3136) {
    const int r = n - 3072;                       // absolute batch row
    const int g = r >> 5, rl = r & 31;
    for (int h = tid; h < 512; h += 256) {
      const int w = h >> 3, c = h & 7;
      // h(-1) -> group g, buf 1
      a.Hbf[(size_t)g*32768 + 16384 + w*256 + rl*8 + c] = f2bf(a.h0[r*512 + h]);
    }
  } else {
    if (tid < 128) a.flag[tid] = 0;
  }
}

__global__ void convx_kernel(const float* __restrict__ x, unsigned short* __restrict__ xbf) {
  const size_t i = ((size_t)blockIdx.x*256 + threadIdx.x) * 4;
  float4 v = *(const float4*)(x + i);
  ushort4 r;
  r.x = f2bf(v.x); r.y = f2bf(v.y); r.z = f2bf(v.z); r.w = f2bf(v.w);
  *(ushort4*)(xbf + i) = r;
}

struct LstmArgs {
  const float* x; const unsigned short* xbf; const float* c0; const int* slen;
  const unsigned short* WT; const float* bias_all; unsigned short* Hbf;
  int* flag; float* P; float* out;
};

__device__ __forceinline__ void gemm_one(const uint4& afr, const char* wlds,
                                         int lane, int bkc, int nt, f32x4& acc) {
  const int bcol = nt*16 + (lane & 15);
  bf16x8 b = *(const bf16x8*)(wlds + bcol*2048 + (((bkc + bcol) & 127) << 4));
  bf16x8 av = *(const bf16x8*)&afr;
  acc = __builtin_amdgcn_mfma_f32_16x16x32_bf16(av, b, acc, 0, 0, 0);
}

__device__ __forceinline__ void gemm_q3(const uint4* af, const char* wlds,
                                        int lane, int kh, f32x4* acc) {
  #pragma unroll
  for (int kt = 0; kt < 8; ++kt) {
    const int bkc = kh*32 + kt*4 + (lane >> 4);
    #pragma unroll
    for (int nt = 0; nt < 3; ++nt) gemm_one(af[kt], wlds, lane, bkc, nt, acc[nt]);
  }
}

__device__ __forceinline__ void load_xf(const LstmArgs& a, bool ux, int t, int q,
                                        int arow, int lane, uint4 xf[8]) {
  #pragma unroll
  for (int kt = 0; kt < 8; ++kt) {
    const size_t off = ((size_t)t*64 + arow)*512 + (size_t)(q*32 + kt*4 + (lane >> 4))*8;
    if (ux) {
      xf[kt] = *(const uint4*)(a.xbf + off);
    } else {
      const float* sp = a.x + off;
      float4 v0 = *(const float4*)(sp);
      float4 v1 = *(const float4*)(sp + 4);
      xf[kt].x = (unsigned)f2bf(v0.x) | ((unsigned)f2bf(v0.y) << 16);
      xf[kt].y = (unsigned)f2bf(v0.z) | ((unsigned)f2bf(v0.w) << 16);
      xf[kt].z = (unsigned)f2bf(v1.x) | ((unsigned)f2bf(v1.y) << 16);
      xf[kt].w = (unsigned)f2bf(v1.z) | ((unsigned)f2bf(v1.w) << 16);
    }
  }
}

__launch_bounds__(256, 1)
__global__ void lstm_kernel(LstmArgs a) {
  extern __shared__ char smem[];
  char*  wlds   = smem + L_WLDS;
  float* Plds   = (float*)(smem + L_PLDS);
  float* gatesA = (float*)(smem + L_GATES);
  float* gatesB = gatesA + 32*53;
  float* part   = (float*)(smem + L_PART);
  float* cstA   = (float*)(smem + L_CST);
  float* cstB   = cstA + 32*9;
  int*   flagA  = a.flag;
  int*   flagB  = a.flag + 64;
  float* blds   = (float*)(smem + L_BLDS);
  int*   slenl  = (int*)(smem + L_SLEN);

  const int wg = blockIdx.x, tid = threadIdx.x;
  const int lane = tid & 63, wv = tid >> 6;
  const int wgrp = wv >> 1;                // this wave's group (0: rows 0-31, 1: rows 32-63)
  const int mt = wv & 1;                   // m-tile within group
  const int arl = mt*16 + (lane & 15);     // group-local A-operand row
  const bool ux = (a.xbf != nullptr);

  // ---- one-time init ----
  for (int m = tid; m < COLS*128; m += 256) {
    const int col = m >> 7, kc = m & 127;
    const int q = col >> 3, cc = col & 7;
    uint4 v = *(const uint4*)(a.WT + ((size_t)(q*512 + wg*8 + cc))*1024 + kc*8);
    *(uint4*)(wlds + col*2048 + (((kc + col) & 127) << 4)) = v;
  }
  if (tid < COLS) blds[tid] = a.bias_all[(tid>>3)*512 + wg*8 + (tid&7)];
  if (tid < 64) slenl[tid] = a.slen[tid];
  for (int e = tid; e < 512; e += 256) {
    const int r = e >> 3, c = e & 7;
    float* cs = (r < 32) ? cstA : cstB;
    cs[(r & 31)*9 + c] = a.c0[(size_t)r*512 + wg*8 + c];
  }
  __syncthreads();

  // ---- prologue: x(0) GEMM per wave's group ----
  f32x4 accC[3] = { f32x4{0,0,0,0}, f32x4{0,0,0,0}, f32x4{0,0,0,0} };
  {
    uint4 xf[8];
    load_xf(a, ux, 0, 0, wgrp*32 + arl, lane, xf);
    gemm_q3(xf, wlds, lane, 0, accC);
    load_xf(a, ux, 0, 1, wgrp*32 + arl, lane, xf);
    gemm_q3(xf, wlds, lane, 1, accC);
  }

  for (int t = 0; t < S_LEN; ++t) {
    const unsigned ep = (unsigned)(t & 1);
    const int buf = (t+1) & 1;
    const int tn = t + 1;
    uint4 hf[16];
    uint4 xf[8];
    f32x4 accN[3] = { f32x4{0,0,0,0}, f32x4{0,0,0,0}, f32x4{0,0,0,0} };
    float hv0 = 0.f, hv1 = 0.f, cv0 = 0.f, cv1 = 0.f;

    // ======== A front ========
    if (tid < 64) { while (ATOM_LD(&flagA[tid]) < t) __builtin_amdgcn_s_sleep(1); }
    __syncthreads();                                                    // bar1

    if (wgrp == 0) {
      const unsigned short* Hb = a.Hbf + (size_t)buf*16384;             // group 0
      #pragma unroll
      for (int j = 0; j < 16; ++j) {
        const int kc = ((j>>3)<<5) + (j&7)*4 + (lane>>4);
        asm volatile("global_load_dwordx4 %0, %1, off sc0 sc1"
                     : "=v"(hf[j]) : "v"(Hb + (size_t)kc*256 + (size_t)arl*8));
      }
      asm volatile("s_waitcnt vmcnt(8)" ::: "memory");
      __builtin_amdgcn_sched_barrier(0);
      #pragma unroll
      for (int kt = 0; kt < 8; ++kt)
        gemm_one(hf[kt], wlds, lane, 64 + kt*4 + (lane>>4), 2, accC[2]);
      asm volatile("s_waitcnt vmcnt(0)" ::: "memory");
      __builtin_amdgcn_sched_barrier(0);
      #pragma unroll
      for (int kt = 0; kt < 8; ++kt)
        gemm_one(hf[8+kt], wlds, lane, 96 + kt*4 + (lane>>4), 2, accC[2]);
      #pragma unroll
      for (int ri = 0; ri < 4; ++ri)
        gatesA[(mt*16 + (lane>>4)*4 + ri)*53 + 32 + (lane&15)] = accC[2][ri];
    }
    __syncthreads();                                                    // bar2

    if (tid < 64) {                   // A softmax partials + publish
      const int gi = tid >> 5, r = tid & 31;
      float s = 0.f;
      #pragma unroll
      for (int c2 = 0; c2 < 8; ++c2) {
        float e = __expf(gatesA[r*53 + 32 + gi*8 + c2] + blds[32 + gi*8 + c2]);
        e = fmaxf(e, 1e-30f);
        gatesA[r*53 + 32 + gi*8 + c2] = e;
        s += e;
      }
      ATOM_ST((unsigned*)(a.P + (size_t)wg*64 + tid), __float_as_uint(s) | (ep << 31));
    }

    if (wgrp == 0) {                  // A fico GEMM + dump
      #pragma unroll
      for (int hh = 0; hh < 2; ++hh)
        #pragma unroll
        for (int kt = 0; kt < 8; ++kt) {
          const int bkc = (2+hh)*32 + kt*4 + (lane>>4);
          gemm_one(hf[hh*8+kt], wlds, lane, bkc, 0, accC[0]);
          gemm_one(hf[hh*8+kt], wlds, lane, bkc, 1, accC[1]);
        }
      #pragma unroll
      for (int nt = 0; nt < 2; ++nt)
        #pragma unroll
        for (int ri = 0; ri < 4; ++ri)
          gatesA[(mt*16 + (lane>>4)*4 + ri)*53 + nt*16 + (lane&15)] = accC[nt][ri];
    }

    // ======== B front (covers A's P round-trip) ========
    if (tid < 64) { while (ATOM_LD(&flagB[tid]) < t) __builtin_amdgcn_s_sleep(1); }
    __syncthreads();                                                    // bar3

    if (wgrp == 1) {
      const unsigned short* Hb = a.Hbf + 32768 + (size_t)buf*16384;     // group 1
      #pragma unroll
      for (int j = 0; j < 16; ++j) {
        const int kc = ((j>>3)<<5) + (j&7)*4 + (lane>>4);
        asm volatile("global_load_dwordx4 %0, %1, off sc0 sc1"
                     : "=v"(hf[j]) : "v"(Hb + (size_t)kc*256 + (size_t)arl*8));
      }
      asm volatile("s_waitcnt vmcnt(8)" ::: "memory");
      __builtin_amdgcn_sched_barrier(0);
      #pragma unroll
      for (int kt = 0; kt < 8; ++kt)
        gemm_one(hf[kt], wlds, lane, 64 + kt*4 + (lane>>4), 2, accC[2]);
      asm volatile("s_waitcnt vmcnt(0)" ::: "memory");
      __builtin_amdgcn_sched_barrier(0);
      #pragma unroll
      for (int kt = 0; kt < 8; ++kt)
        gemm_one(hf[8+kt], wlds, lane, 96 + kt*4 + (lane>>4), 2, accC[2]);
      #pragma unroll
      for (int ri = 0; ri < 4; ++ri)
        gatesB[(mt*16 + (lane>>4)*4 + ri)*53 + 32 + (lane&15)] = accC[2][ri];
    }
    __syncthreads();                                                    // bar4

    if (tid < 64) {                   // B softmax partials + publish
      const int gi = tid >> 5, r = tid & 31;
      float s = 0.f;
      #pragma unroll
      for (int c2 = 0; c2 < 8; ++c2) {
        float e = __expf(gatesB[r*53 + 32 + gi*8 + c2] + blds[32 + gi*8 + c2]);
        e = fmaxf(e, 1e-30f);
        gatesB[r*53 + 32 + gi*8 + c2] = e;
        s += e;
      }
      ATOM_ST((unsigned*)(a.P + 4096 + (size_t)wg*64 + tid), __float_as_uint(s) | (ep << 31));
    }

    if (wgrp == 1) {                  // B fico GEMM + dump
      #pragma unroll
      for (int hh = 0; hh < 2; ++hh)
        #pragma unroll
        for (int kt = 0; kt < 8; ++kt) {
          const int bkc = (2+hh)*32 + kt*4 + (lane>>4);
          gemm_one(hf[hh*8+kt], wlds, lane, bkc, 0, accC[0]);
          gemm_one(hf[hh*8+kt], wlds, lane, bkc, 1, accC[1]);
        }
      #pragma unroll
      for (int nt = 0; nt < 2; ++nt)
        #pragma unroll
        for (int ri = 0; ri < 4; ++ri)
          gatesB[(mt*16 + (lane>>4)*4 + ri)*53 + nt*16 + (lane&15)] = accC[nt][ri];
    }

    // A transform (gatesA[0..31] dumped before bar3)
    #pragma unroll
    for (int j = 0; j < 4; ++j) {
      const int m2 = tid + j*256;
      const int r = m2 >> 5, c2 = m2 & 31;
      const float v = gatesA[r*53 + c2] + blds[c2];
      const float e = __expf((c2 < 24) ? -v : 2.f*v);
      gatesA[r*53 + c2] = (c2 < 24) ? 1.f/(1.f+e) : (e-1.f)/(e+1.f);
    }

    // ======== A back ========
    {                                  // A P-poll + stage
      uint4 pbuf[4];
      const float* Pg = a.P;
      bool ok = false;
      do {
        #pragma unroll
        for (int j = 0; j < 4; ++j)
          asm volatile("global_load_dwordx4 %0, %1, off sc0 sc1"
                       : "=v"(pbuf[j]) : "v"(Pg + (size_t)tid*16 + j*4));
        asm volatile("s_waitcnt vmcnt(0)" ::: "memory");
        __builtin_amdgcn_sched_barrier(0);
        unsigned agg = ep ? 0xFFFFFFFFu : 0u;
        #pragma unroll
        for (int j = 0; j < 4; ++j) {
          if (ep) agg &= (pbuf[j].x & pbuf[j].y & pbuf[j].z & pbuf[j].w);
          else    agg |= (pbuf[j].x | pbuf[j].y | pbuf[j].z | pbuf[j].w);
        }
        ok = ((agg >> 31) == ep);
        if (!ok) __builtin_amdgcn_s_sleep(1);
      } while (!ok);
      #pragma unroll
      for (int j = 0; j < 4; ++j)
        *(uint4*)(Plds + (size_t)(tid>>2)*68 + (tid&3)*16 + j*4) = pbuf[j];
    }
    __syncthreads();                                                    // bar5

    {                                  // A prefix partials
      const int combo = tid >> 2, q = tid & 3;
      float tot = 0.f, offv = 0.f;
      #pragma unroll
      for (int i = 0; i < 16; ++i) {
        const int w = q*16 + i;
        const float v = __builtin_fabsf(Plds[w*68 + combo]);
        tot += v;
        if (w < wg) offv += v;
      }
      *(float2*)(part + tid*2) = make_float2(tot, offv);
    }
    __syncthreads();                                                    // bar6
    if (tid < 64) {                    // A cumsum -> m
      const int gi = tid >> 5, r = tid & 31;
      float4 p0 = *(const float4*)(part + tid*8);
      float4 p1 = *(const float4*)(part + tid*8 + 4);
      const float inv = 1.f / (p0.x + p0.z + p1.x + p1.z);
      float run = p0.y + p0.w + p1.y + p1.w;
      #pragma unroll
      for (int c2 = 0; c2 < 8; ++c2) {
        run += gatesA[r*53 + 32 + gi*8 + c2];
        gatesA[r*53 + 32 + gi*8 + c2] = run * inv;
      }
    }
    __syncthreads();                                                    // bar7

    if (tid < 128) {                   // A update + Hbf publish
      const int r = (tid >> 2) & 31, eu = tid & 3;
      const float* gg = gatesA + r*53;
      float hvv[2], cvv[2];
      #pragma unroll
      for (int u = 0; u < 2; ++u) {
        const int c2 = eu*2 + u;
        const float ft = gg[c2], it = gg[8+c2], ot = gg[16+c2], ch = gg[24+c2];
        const float mf = gg[32+c2], mi = gg[40+c2];
        const float w2 = mf * mi;
        const float cn = (ft*w2 + (mf - w2))*cstA[r*9+c2] + (it*w2 + (mi - w2))*ch;
        cstA[r*9+c2] = cn; cvv[u] = cn; hvv[u] = ot*cn;
      }
      hv0 = hvv[0]; hv1 = hvv[1]; cv0 = cvv[0]; cv1 = cvv[1];
      const unsigned pk = (unsigned)f2bf(hvv[0]) | ((unsigned)f2bf(hvv[1]) << 16);
      ATOM_ST((unsigned*)(a.Hbf + (size_t)(t&1)*16384 + wg*256 + r*8 + eu*2), pk);
    }
    asm volatile("s_waitcnt vmcnt(0)" ::: "memory");
    __syncthreads();                                                    // bar8
    if (tid == 0) ATOM_ST(&flagA[wg], t+1);

    // B transform + A x(t+1) GEMM (covers A's h RT)
    #pragma unroll
    for (int j = 0; j < 4; ++j) {
      const int m2 = tid + j*256;
      const int r = m2 >> 5, c2 = m2 & 31;
      const float v = gatesB[r*53 + c2] + blds[c2];
      const float e = __expf((c2 < 24) ? -v : 2.f*v);
      gatesB[r*53 + c2] = (c2 < 24) ? 1.f/(1.f+e) : (e-1.f)/(e+1.f);
    }
    if (wgrp == 0 && tn < S_LEN) {
      load_xf(a, ux, tn, 0, arl, lane, xf);
      gemm_q3(xf, wlds, lane, 0, accN);
      load_xf(a, ux, tn, 1, arl, lane, xf);
      gemm_q3(xf, wlds, lane, 1, accN);
    }

    // ======== B back ========
    {                                  // B P-poll + stage
      uint4 pbuf[4];
      const float* Pg = a.P + 4096;
      bool ok = false;
      do {
        #pragma unroll
        for (int j = 0; j < 4; ++j)
          asm volatile("global_load_dwordx4 %0, %1, off sc0 sc1"
                       : "=v"(pbuf[j]) : "v"(Pg + (size_t)tid*16 + j*4));
        asm volatile("s_waitcnt vmcnt(0)" ::: "memory");
        __builtin_amdgcn_sched_barrier(0);
        unsigned agg = ep ? 0xFFFFFFFFu : 0u;
        #pragma unroll
        for (int j = 0; j < 4; ++j) {
          if (ep) agg &= (pbuf[j].x & pbuf[j].y & pbuf[j].z & pbuf[j].w);
          else    agg |= (pbuf[j].x | pbuf[j].y | pbuf[j].z | pbuf[j].w);
        }
        ok = ((agg >> 31) == ep);
        if (!ok) __builtin_amdgcn_s_sleep(1);
      } while (!ok);
      #pragma unroll
      for (int j = 0; j < 4; ++j)
        *(uint4*)(Plds + (size_t)(tid>>2)*68 + (tid&3)*16 + j*4) = pbuf[j];
    }
    __syncthreads();                                                    // bar9

    {                                  // B prefix partials
      const int combo = tid >> 2, q = tid & 3;
      float tot = 0.f, offv = 0.f;
      #pragma unroll
      for (int i = 0; i < 16; ++i) {
        const int w = q*16 + i;
        const float v = __builtin_fabsf(Plds[w*68 + combo]);
        tot += v;
        if (w < wg) offv += v;
      }
      *(float2*)(part + tid*2) = make_float2(tot, offv);
    }
    __syncthreads();                                                    // bar10
    if (tid < 64) {                    // B cumsum -> m
      const int gi = tid >> 5, r = tid & 31;
      float4 p0 = *(const float4*)(part + tid*8);
      float4 p1 = *(const float4*)(part + tid*8 + 4);
      const float inv = 1.f / (p0.x + p0.z + p1.x + p1.z);
      float run = p0.y + p0.w + p1.y + p1.w;
      #pragma unroll
      for (int c2 = 0; c2 < 8; ++c2) {
        run += gatesB[r*53 + 32 + gi*8 + c2];
        gatesB[r*53 + 32 + gi*8 + c2] = run * inv;
      }
    }
    __syncthreads();                                                    // bar11

    if (tid >= 128) {                  // B update + Hbf publish
      const int r = (tid >> 2) & 31, eu = tid & 3;
      const float* gg = gatesB + r*53;
      float hvv[2], cvv[2];
      #pragma unroll
      for (int u = 0; u < 2; ++u) {
        const int c2 = eu*2 + u;
        const float ft = gg[c2], it = gg[8+c2], ot = gg[16+c2], ch = gg[24+c2];
        const float mf = gg[32+c2], mi = gg[40+c2];
        const float w2 = mf * mi;
        const float cn = (ft*w2 + (mf - w2))*cstB[r*9+c2] + (it*w2 + (mi - w2))*ch;
        cstB[r*9+c2] = cn; cvv[u] = cn; hvv[u] = ot*cn;
      }
      hv0 = hvv[0]; hv1 = hvv[1]; cv0 = cvv[0]; cv1 = cvv[1];
      const unsigned pk = (unsigned)f2bf(hvv[0]) | ((unsigned)f2bf(hvv[1]) << 16);
      ATOM_ST((unsigned*)(a.Hbf + 32768 + (size_t)(t&1)*16384 + wg*256 + r*8 + eu*2), pk);
    }
    asm volatile("s_waitcnt vmcnt(0)" ::: "memory");
    __syncthreads();                                                    // bar12
    if (tid == 0) ATOM_ST(&flagB[wg], t+1);

    // B x(t+1) GEMM (covers B's h RT) + output writes
    if (wgrp == 1 && tn < S_LEN) {
      load_xf(a, ux, tn, 0, 32 + arl, lane, xf);
      gemm_q3(xf, wlds, lane, 0, accN);
      load_xf(a, ux, tn, 1, 32 + arl, lane, xf);
      gemm_q3(xf, wlds, lane, 1, accN);
    }
    {
      const int g = tid >> 7, r = (tid >> 2) & 31, eu = tid & 3;
      const int abr = g*32 + r;
      const int col = wg*8 + eu*2;
      *(float2*)(a.out + (size_t)t*32768 + abr*512 + col) = make_float2(hv0, hv1);
      if (t == slenl[abr] - 1) {
        *(float2*)(a.out + (size_t)OUT_SH + abr*512 + col) = make_float2(hv0, hv1);
        *(float2*)(a.out + (size_t)OUT_SC + abr*512 + col) = make_float2(cv0, cv1);
      }
    }

    accC[0] = accN[0]; accC[1] = accN[1]; accC[2] = accN[2];
  }
}

// ---------------- host ----------------
extern "C" void kernel_launch(void* const* d_in, const int* in_sizes, int n_in,
                              void* d_out, int out_size, void* d_ws, size_t ws_size,
                              hipStream_t stream) {
  char* ws = (char*)d_ws;

  PrepArgs pa;
  for (int q = 0; q < 6; ++q) {
    pa.W[q]   = (const float*)d_in[3 + 2*q];
    pa.bia[q] = (const float*)d_in[4 + 2*q];
  }
  pa.h0       = (const float*)d_in[1];
  pa.WT       = (unsigned short*)(ws + O_WT);
  pa.bias_all = (float*)(ws + O_BIAS);
  pa.Hbf      = (unsigned short*)(ws + O_HBF);
  pa.flag     = (int*)(ws + O_FLAG);
  prep_kernel<<<3137, 256, 0, stream>>>(pa);

  const bool ux = (ws_size >= WS_FULL);
  if (ux)
    convx_kernel<<<16384, 256, 0, stream>>>((const float*)d_in[0], (unsigned short*)(ws + O_XBF));

  LstmArgs la;
  la.x        = (const float*)d_in[0];
  la.xbf      = ux ? (const unsigned short*)(ws + O_XBF) : nullptr;
  la.c0       = (const float*)d_in[2];
  la.slen     = (const int*)d_in[15];
  la.WT       = pa.WT;
  la.bias_all = pa.bias_all;
  la.Hbf      = pa.Hbf;
  la.flag     = pa.flag;
  la.P        = (float*)(ws + O_P);
  la.out      = (float*)d_out;

  hipFuncSetAttribute(reinterpret_cast<const void*>(lstm_kernel),
                      hipFuncAttributeMaxDynamicSharedMemorySize, SMEM_TOTAL);
  lstm_kernel<<<NWG, 256, SMEM_TOTAL, stream>>>(la);
}

// Round 10
// 4123.212 us; speedup vs baseline: 1.7240x; 1.7240x over previous
//
#include <hip/hip_runtime.h>

// ---------------- problem constants ----------------
#define S_LEN 512
#define NWG   64
#define COLS  48
#define OUT_ALLH (512*64*512)
#define OUT_SH   (OUT_ALLH)
#define OUT_SC   (OUT_ALLH + 64*512)

// ---------------- ws layout (bytes) ----------------
#define O_WT    0ull
#define SZ_WT   (3072ull*1024*2)
#define O_BIAS  (O_WT + SZ_WT)
#define SZ_BIAS (3072ull*4)
#define O_HBF   (O_BIAS + SZ_BIAS)           // bf16 [buf][writer][row][8col]
#define SZ_HBF  (2ull*64*512*2)
#define O_FLAGH (O_HBF + SZ_HBF)             // packed 64 ints
#define O_P     (O_FLAGH + 256)              // [wg][gate*64+row] f32, epoch sign
#define SZ_P    (64ull*128*4)
#define O_XBF   (O_P + SZ_P)
#define SZ_XBF  (512ull*64*512*2)
#define WS_FULL (O_XBF + SZ_XBF)

// ---------------- LDS layout (bytes) ----------------
#define L_WLDS  0                 // 98304
#define L_PLDS  98304             // 64*132*4 = 33792
#define L_GATES 132096            // 64*53*4  = 13568
#define L_CST   145664            // 64*9*4   = 2304
#define L_BLDS  147968            // 192
#define L_SLEN  148160            // 256
#define L_PART  148416            // 256*8    = 2048
#define SMEM_TOTAL 150464

#define GSTR 53
#define PSTR 132

typedef short bf16x8 __attribute__((ext_vector_type(8)));
typedef float f32x4  __attribute__((ext_vector_type(4)));

__device__ __forceinline__ unsigned short f2bf(float f) {
  unsigned u = __float_as_uint(f);
  u += 0x7fffu + ((u >> 16) & 1u);
  return (unsigned short)(u >> 16);
}

#define ATOM_LD(p)    __hip_atomic_load((p), __ATOMIC_RELAXED, __HIP_MEMORY_SCOPE_AGENT)
#define ATOM_ST(p, v) __hip_atomic_store((p), (v), __ATOMIC_RELAXED, __HIP_MEMORY_SCOPE_AGENT)

struct PrepArgs {
  const float* W[6]; const float* bia[6];
  const float* h0;
  unsigned short* WT; float* bias_all; unsigned short* Hbf;
  int* flagH;
};

__global__ void prep_kernel(PrepArgs a) {
  const int n = blockIdx.x, tid = threadIdx.x;
  if (n < 3072) {
    const int q = n >> 9, col = n & 511;
    const float* Wq = a.W[q];
    for (int k = tid; k < 1024; k += 256)
      a.WT[(size_t)n*1024 + k] = f2bf(Wq[k*512 + col]);
    if (tid == 0) a.bias_all[n] = a.bia[q][col];
  } else if (n < 3136) {
    const int r = n - 3072;
    for (int h = tid; h < 512; h += 256) {
      const int w = h >> 3, c = h & 7;
      a.Hbf[(size_t)(64 + w)*512 + r*8 + c] = f2bf(a.h0[r*512 + h]);  // buf1 = h_{-1}
    }
  } else {
    if (tid < 64) a.flagH[tid] = 0;
  }
}

__global__ void convx_kernel(const float* __restrict__ x, unsigned short* __restrict__ xbf) {
  const size_t i = ((size_t)blockIdx.x*256 + threadIdx.x) * 4;
  float4 v = *(const float4*)(x + i);
  ushort4 r;
  r.x = f2bf(v.x); r.y = f2bf(v.y); r.z = f2bf(v.z); r.w = f2bf(v.w);
  *(ushort4*)(xbf + i) = r;
}

struct LstmArgs {
  const float* x; const unsigned short* xbf; const float* c0; const int* slen;
  const unsigned short* WT; const float* bias_all; unsigned short* Hbf;
  int* flagH; float* P; float* out;
};

__device__ __forceinline__ void gemm_q(const uint4* af, const char* wlds,
                                       int lane, int kh, f32x4* acc) {
  #pragma unroll
  for (int kt = 0; kt < 8; ++kt) {
    bf16x8 a = *(const bf16x8*)&af[kt];
    #pragma unroll
    for (int nt = 0; nt < 3; ++nt) {
      const int bcol = nt*16 + (lane & 15);
      const int bkc  = kh*32 + kt*4 + (lane >> 4);
      bf16x8 b = *(const bf16x8*)(wlds + bcol*2048 + (((bkc + bcol) & 127) << 4));
      acc[nt] = __builtin_amdgcn_mfma_f32_16x16x32_bf16(a, b, acc[nt], 0, 0, 0);
    }
  }
}

__device__ __forceinline__ void load_xf(const LstmArgs& a, bool ux, int t, int q,
                                        int arow, int lane, uint4 xf[8]) {
  #pragma unroll
  for (int kt = 0; kt < 8; ++kt) {
    const size_t off = ((size_t)t*64 + arow)*512 + (size_t)(q*32 + kt*4 + (lane >> 4))*8;
    if (ux) {
      xf[kt] = *(const uint4*)(a.xbf + off);
    } else {
      const float* sp = a.x + off;
      float4 v0 = *(const float4*)(sp);
      float4 v1 = *(const float4*)(sp + 4);
      xf[kt].x = (unsigned)f2bf(v0.x) | ((unsigned)f2bf(v0.y) << 16);
      xf[kt].y = (unsigned)f2bf(v0.z) | ((unsigned)f2bf(v0.w) << 16);
      xf[kt].z = (unsigned)f2bf(v1.x) | ((unsigned)f2bf(v1.y) << 16);
      xf[kt].w = (unsigned)f2bf(v1.z) | ((unsigned)f2bf(v1.w) << 16);
    }
  }
}

__launch_bounds__(256, 1)
__global__ void lstm_kernel(LstmArgs a) {
  extern __shared__ char smem[];
  char*  wlds  = smem + L_WLDS;
  float* Plds  = (float*)(smem + L_PLDS);
  float* gates = (float*)(smem + L_GATES);
  float* cst   = (float*)(smem + L_CST);
  float* blds  = (float*)(smem + L_BLDS);
  int*   slenl = (int*)(smem + L_SLEN);
  float* part  = (float*)(smem + L_PART);

  const int wg = blockIdx.x, tid = threadIdx.x;
  const int lane = tid & 63, wv = tid >> 6;
  const int arow = wv*16 + (lane & 15);
  const bool ux = (a.xbf != nullptr);

  for (int m = tid; m < COLS*128; m += 256) {
    const int col = m >> 7, kc = m & 127;
    const int q = col >> 3, c = col & 7;
    uint4 v = *(const uint4*)(a.WT + ((size_t)(q*512 + wg*8 + c))*1024 + kc*8);
    *(uint4*)(wlds + col*2048 + (((kc + col) & 127) << 4)) = v;
  }
  if (tid < COLS) { const int q = tid >> 3, c = tid & 7; blds[tid] = a.bias_all[q*512 + wg*8 + c]; }
  if (tid < 64) slenl[tid] = a.slen[tid];
  for (int e = tid; e < 512; e += 256) { const int r = e >> 3, c = e & 7; cst[r*9 + c] = a.c0[r*512 + wg*8 + c]; }
  __syncthreads();

  f32x4 accC[3] = { f32x4{0,0,0,0}, f32x4{0,0,0,0}, f32x4{0,0,0,0} };
  {
    uint4 xf[8];
    load_xf(a, ux, 0, 0, arow, lane, xf);
    gemm_q(xf, wlds, lane, 0, accC);
    load_xf(a, ux, 0, 1, arow, lane, xf);
    gemm_q(xf, wlds, lane, 1, accC);
  }

  for (int t = 0; t < S_LEN; ++t) {
    if (tid < 64) {
      while (ATOM_LD(&a.flagH[tid]) < t) { }
    }
    __syncthreads();

    const int buf = (t+1) & 1;
    const int tn = t + 1;
    const int tc = (tn < S_LEN) ? tn : (S_LEN - 1);
    uint4 hf[16];
    uint4 xfa[8], xfb[8];

    if (ux) {
      #pragma unroll
      for (int j = 0; j < 16; ++j) {
        const int wl = (j & 7)*4 + (lane >> 4) + ((j >> 3) << 5);
        const unsigned short* src = a.Hbf + ((size_t)(buf*64 + wl))*512 + (size_t)arow*8;
        asm volatile("global_load_dwordx4 %0, %1, off sc0 sc1" : "=v"(hf[j]) : "v"(src));
      }
      #pragma unroll
      for (int kt = 0; kt < 8; ++kt) {
        const unsigned short* src = a.xbf + ((size_t)tc*64 + arow)*512 + (size_t)(kt*4 + (lane >> 4))*8;
        asm volatile("global_load_dwordx4 %0, %1, off" : "=v"(xfa[kt]) : "v"(src));
      }
      #pragma unroll
      for (int kt = 0; kt < 8; ++kt) {
        const unsigned short* src = a.xbf + ((size_t)tc*64 + arow)*512 + (size_t)(32 + kt*4 + (lane >> 4))*8;
        asm volatile("global_load_dwordx4 %0, %1, off" : "=v"(xfb[kt]) : "v"(src));
      }
      asm volatile("s_waitcnt vmcnt(24)" ::: "memory");
      __builtin_amdgcn_sched_barrier(0);
      gemm_q(&hf[0], wlds, lane, 2, accC);
      asm volatile("s_waitcnt vmcnt(16)" ::: "memory");
      __builtin_amdgcn_sched_barrier(0);
      gemm_q(&hf[8], wlds, lane, 3, accC);
    } else {
      #pragma unroll
      for (int j = 0; j < 16; ++j) {
        const int wl = (j & 7)*4 + (lane >> 4) + ((j >> 3) << 5);
        const unsigned short* src = a.Hbf + ((size_t)(buf*64 + wl))*512 + (size_t)arow*8;
        asm volatile("global_load_dwordx4 %0, %1, off sc0 sc1" : "=v"(hf[j]) : "v"(src));
      }
      asm volatile("s_waitcnt vmcnt(8)" ::: "memory");
      __builtin_amdgcn_sched_barrier(0);
      gemm_q(&hf[0], wlds, lane, 2, accC);
      asm volatile("s_waitcnt vmcnt(0)" ::: "memory");
      __builtin_amdgcn_sched_barrier(0);
      gemm_q(&hf[8], wlds, lane, 3, accC);
    }

    #pragma unroll
    for (int nt = 0; nt < 3; ++nt)
      #pragma unroll
      for (int ri = 0; ri < 4; ++ri) {
        const int row = wv*16 + (lane >> 4)*4 + ri;
        gates[row*GSTR + nt*16 + (lane & 15)] = accC[nt][ri];
      }
    __syncthreads();

    const unsigned ep = (unsigned)(t & 1);

    if (tid < 128) {
      const int gi = tid >> 6, r = tid & 63;
      float s = 0.f;
      #pragma unroll
      for (int c = 0; c < 8; ++c) {
        float e = __expf(gates[r*GSTR + (4+gi)*8 + c] + blds[(4+gi)*8 + c]);
        e = fmaxf(e, 1e-30f);
        gates[r*GSTR + (4+gi)*8 + c] = e;
        s += e;
      }
      ATOM_ST((unsigned*)(a.P + (size_t)wg*128 + tid), __float_as_uint(s) | (ep << 31));
    }

    f32x4 accN[3] = { f32x4{0,0,0,0}, f32x4{0,0,0,0}, f32x4{0,0,0,0} };
    uint4 xf[8];
    if (ux) {
      asm volatile("s_waitcnt vmcnt(8)" ::: "memory");
      __builtin_amdgcn_sched_barrier(0);
      gemm_q(xfa, wlds, lane, 0, accN);
    } else if (tn < S_LEN) {
      load_xf(a, ux, tn, 0, arow, lane, xf);
      gemm_q(xf, wlds, lane, 0, accN);
    }

    #pragma unroll
    for (int j = 0; j < 8; ++j) {
      const int m2 = tid + j*256;
      const int r = m2 >> 5, c = m2 & 31;
      const float v = gates[r*GSTR + c] + blds[c];
      const float e = __expf((c < 24) ? -v : 2.f*v);
      gates[r*GSTR + c] = (c < 24) ? 1.f/(1.f+e) : (e-1.f)/(e+1.f);
    }

    uint4 pbuf[8];
    {
      bool ok = false;
      do {
        #pragma unroll
        for (int j = 0; j < 8; ++j) {
          const int idx = tid + j*256;
          const float* src = a.P + (size_t)idx*4;
          asm volatile("global_load_dwordx4 %0, %1, off sc0 sc1" : "=v"(pbuf[j]) : "v"(src));
        }
        asm volatile("s_waitcnt vmcnt(0)" ::: "memory");
        __builtin_amdgcn_sched_barrier(0);
        unsigned agg = ep ? 0xFFFFFFFFu : 0u;
        #pragma unroll
        for (int j = 0; j < 8; ++j) {
          if (ep) agg &= (pbuf[j].x & pbuf[j].y & pbuf[j].z & pbuf[j].w);
          else    agg |= (pbuf[j].x | pbuf[j].y | pbuf[j].z | pbuf[j].w);
        }
        ok = ((agg >> 31) == ep);
      } while (!ok);
    }

    #pragma unroll
    for (int j = 0; j < 8; ++j) {
      const int idx = tid + j*256;
      const int w = idx >> 5, o = (idx & 31)*4;
      *(uint4*)((char*)Plds + ((size_t)w*PSTR + o)*4) = pbuf[j];
    }
    __syncthreads();

    {
      const int p = tid >> 1, half = tid & 1;
      float tot = 0.f, offv = 0.f;
      #pragma unroll
      for (int i = 0; i < 32; ++i) {
        const int w = half*32 + i;
        const float v = __builtin_fabsf(Plds[w*PSTR + p]);
        tot += v;
        if (w < wg) offv += v;
      }
      *(float2*)(part + tid*2) = make_float2(tot, offv);
    }
    __syncthreads();
    if (tid < 128) {
      const int gi = tid >> 6, r = tid & 63;
      float4 pp = *(const float4*)(part + tid*4);
      const float inv = 1.f / (pp.x + pp.z);
      float run = pp.y + pp.w;
      #pragma unroll
      for (int c = 0; c < 8; ++c) {
        run += gates[r*GSTR + (4+gi)*8 + c];
        gates[r*GSTR + (4+gi)*8 + c] = run * inv;
      }
    }
    __syncthreads();

    float hv[2], cv2[2];
    const int er = tid >> 2, ec0 = (tid & 3)*2;
    {
      const float* g = gates + er*GSTR;
      #pragma unroll
      for (int u = 0; u < 2; ++u) {
        const int c = ec0 + u;
        const float ft = g[c];
        const float it = g[8 + c];
        const float ot = g[16 + c];
        const float ch = g[24 + c];
        const float mf = g[32 + c];
        const float mi = g[40 + c];
        const float w2 = mf * mi;
        const float fh = ft * w2 + (mf - w2);
        const float ih = it * w2 + (mi - w2);
        const float cn = fh * cst[er*9 + c] + ih * ch;
        cst[er*9 + c] = cn;
        cv2[u] = cn;
        hv[u] = ot * cn;
      }
      const unsigned pk = (unsigned)f2bf(hv[0]) | ((unsigned)f2bf(hv[1]) << 16);
      ATOM_ST((unsigned*)(a.Hbf + ((size_t)((t & 1)*64 + wg))*512 + er*8 + ec0), pk);
    }
    asm volatile("s_waitcnt vmcnt(0)" ::: "memory");
    __syncthreads();
    if (tid == 0) ATOM_ST(&a.flagH[wg], t+1);

    if (ux) {
      gemm_q(xfb, wlds, lane, 1, accN);
    } else if (tn < S_LEN) {
      load_xf(a, ux, tn, 1, arow, lane, xf);
      gemm_q(xf, wlds, lane, 1, accN);
    }

    {
      const int col = wg*8 + ec0;
      *(float2*)(a.out + (size_t)t*32768 + er*512 + col) = make_float2(hv[0], hv[1]);
      if (t == slenl[er] - 1) {
        *(float2*)(a.out + (size_t)OUT_SH + er*512 + col) = make_float2(hv[0], hv[1]);
        *(float2*)(a.out + (size_t)OUT_SC + er*512 + col) = make_float2(cv2[0], cv2[1]);
      }
    }

    accC[0] = accN[0]; accC[1] = accN[1]; accC[2] = accN[2];
  }
}

extern "C" void kernel_launch(void* const* d_in, const int* in_sizes, int n_in,
                              void* d_out, int out_size, void* d_ws, size_t ws_size,
                              hipStream_t stream) {
  char* ws = (char*)d_ws;

  PrepArgs pa;
  for (int q = 0; q < 6; ++q) {
    pa.W[q]   = (const float*)d_in[3 + 2*q];
    pa.bia[q] = (const float*)d_in[4 + 2*q];
  }
  pa.h0       = (const float*)d_in[1];
  pa.WT       = (unsigned short*)(ws + O_WT);
  pa.bias_all = (float*)(ws + O_BIAS);
  pa.Hbf      = (unsigned short*)(ws + O_HBF);
  pa.flagH    = (int*)(ws + O_FLAGH);
  prep_kernel<<<3137, 256, 0, stream>>>(pa);

  const bool ux = (ws_size >= WS_FULL);
  if (ux)
    convx_kernel<<<16384, 256, 0, stream>>>((const float*)d_in[0], (unsigned short*)(ws + O_XBF));

  LstmArgs la;
  la.x        = (const float*)d_in[0];
  la.xbf      = ux ? (const unsigned short*)(ws + O_XBF) : nullptr;
  la.c0       = (const float*)d_in[2];
  la.slen     = (const int*)d_in[15];
  la.WT       = pa.WT;
  la.bias_all = pa.bias_all;
  la.Hbf      = pa.Hbf;
  la.flagH    = pa.flagH;
  la.P        = (float*)(ws + O_P);
  la.out      = (float*)d_out;

  hipFuncSetAttribute(reinterpret_cast<const void*>(lstm_kernel),
                      hipFuncAttributeMaxDynamicSharedMemorySize, SMEM_TOTAL);
  lstm_kernel<<<NWG, 256, SMEM_TOTAL, stream>>>(la);
}